// Round 1
// baseline (411.600 us; speedup 1.0000x reference)
//
#include <hip/hip_runtime.h>
#include <math.h>

#define BATCH 16
#define CH    64
#define MM    65536          // 256*256
#define PSTRIDE 4160         // 64*64 gram + 64 sums per partial block

// ---------------------------------------------------------------------------
// Kernel 1: per-(batch, m-chunk) partial Gram + channel sums.
// Block = 256 threads (4 waves). Each wave processes a disjoint 16-m subset of
// each 64-m LDS tile and accumulates the FULL 64x64 Gram in 8x8 per-lane
// register tiles; waves are reduced through LDS at the end. Deterministic
// (no float atomics).
// ---------------------------------------------------------------------------
__global__ __launch_bounds__(256) void gram_partial(const float* __restrict__ x,
                                                    float* __restrict__ part,
                                                    int nchunk, int chunk_m) {
    int blk = blockIdx.x;
    int b = blk / nchunk, chunk = blk % nchunk;
    const float* xb = x + (size_t)b * CH * MM + (size_t)chunk * chunk_m;

    __shared__ float xs[CH][65];   // stride 65 -> conflict-free broadcast reads
    __shared__ float sbuf[256];

    int t = threadIdx.x;
    int wave = t >> 6, lane = t & 63;
    int ty = lane >> 3, tx = lane & 7;
    int r0 = ty * 8, c0 = tx * 8;
    int cs = t & 63;           // channel this thread sums
    int msub = wave * 16;      // m-offset for this wave within a tile

    float acc[8][8];
#pragma unroll
    for (int i = 0; i < 8; ++i)
#pragma unroll
        for (int j = 0; j < 8; ++j) acc[i][j] = 0.f;
    float ssum = 0.f;

    int ntile = chunk_m >> 6;
    for (int tile = 0; tile < ntile; ++tile) {
        int mbase = tile << 6;
        __syncthreads();
        // stage 64 channels x 64 m into LDS (coalesced float4 loads)
#pragma unroll
        for (int r = 0; r < 4; ++r) {
            int idx4 = t + r * 256;          // 0..1023 float4 slots
            int c = idx4 >> 4;
            int mi = (idx4 & 15) << 2;
            const float4 v = *reinterpret_cast<const float4*>(
                xb + (size_t)c * MM + mbase + mi);
            xs[c][mi]     = v.x;
            xs[c][mi + 1] = v.y;
            xs[c][mi + 2] = v.z;
            xs[c][mi + 3] = v.w;
        }
        __syncthreads();
#pragma unroll 4
        for (int mm = 0; mm < 16; ++mm) {
            int m = msub + mm;
            float a[8], bb[8];
#pragma unroll
            for (int i = 0; i < 8; ++i) a[i] = xs[r0 + i][m];
#pragma unroll
            for (int j = 0; j < 8; ++j) bb[j] = xs[c0 + j][m];
#pragma unroll
            for (int i = 0; i < 8; ++i)
#pragma unroll
                for (int j = 0; j < 8; ++j)
                    acc[i][j] = fmaf(a[i], bb[j], acc[i][j]);
            ssum += xs[cs][m];
        }
    }

    // cross-wave reduction of the Gram through xs (reused as 64x65 staging)
    __syncthreads();
    for (int w = 0; w < 4; ++w) {
        if (wave == w) {
#pragma unroll
            for (int i = 0; i < 8; ++i)
#pragma unroll
                for (int j = 0; j < 8; ++j) {
                    if (w == 0) xs[r0 + i][c0 + j] = acc[i][j];
                    else        xs[r0 + i][c0 + j] += acc[i][j];
                }
        }
        __syncthreads();
    }
    sbuf[t] = ssum;
    __syncthreads();

    float* op = part + (size_t)blk * PSTRIDE;
#pragma unroll
    for (int r = 0; r < 16; ++r) {
        int e = t + r * 256;
        op[e] = xs[e >> 6][e & 63];
    }
    if (t < 64)
        op[4096 + t] = sbuf[t] + sbuf[t + 64] + sbuf[t + 128] + sbuf[t + 192];
}

// ---------------------------------------------------------------------------
// Kernel 2: per-batch — reduce partials -> cov -> Newton-Schulz(5) -> row-mean
// -> FC1(relu) -> FC2(sigmoid) -> att[b][c].  One block per batch, 256 thr.
// ---------------------------------------------------------------------------
__device__ __forceinline__ void mm64(const float* A, const float* Bm, float* Cm,
                                     int t) {
    // C = A @ B, all 64x64 in LDS with row stride 65. 4x4 register tiles.
    __syncthreads();   // operands ready
    int ty = t >> 4, tx = t & 15;
    int r0 = ty * 4, c0 = tx * 4;
    float acc[4][4];
#pragma unroll
    for (int i = 0; i < 4; ++i)
#pragma unroll
        for (int j = 0; j < 4; ++j) acc[i][j] = 0.f;
    for (int k = 0; k < 64; ++k) {
        float a[4], bb[4];
#pragma unroll
        for (int i = 0; i < 4; ++i) a[i] = A[(r0 + i) * 65 + k];
#pragma unroll
        for (int j = 0; j < 4; ++j) bb[j] = Bm[k * 65 + c0 + j];
#pragma unroll
        for (int i = 0; i < 4; ++i)
#pragma unroll
            for (int j = 0; j < 4; ++j)
                acc[i][j] = fmaf(a[i], bb[j], acc[i][j]);
    }
#pragma unroll
    for (int i = 0; i < 4; ++i)
#pragma unroll
        for (int j = 0; j < 4; ++j) Cm[(r0 + i) * 65 + c0 + j] = acc[i][j];
    __syncthreads();   // result visible
}

__global__ __launch_bounds__(256) void ns_att(const float* __restrict__ part,
                                              const float* __restrict__ w1,
                                              const float* __restrict__ b1,
                                              const float* __restrict__ w2,
                                              const float* __restrict__ b2,
                                              float* __restrict__ att,
                                              int nchunk) {
    __shared__ float BUF[5][64 * 65];
    __shared__ float sv[64];
    __shared__ float hid8[8];
    __shared__ float scal[2];

    int b = blockIdx.x, t = threadIdx.x;
    const float* pb = part + (size_t)b * nchunk * PSTRIDE;

    // channel sums
    if (t < 64) {
        float s = 0.f;
        for (int ch = 0; ch < nchunk; ++ch) s += pb[(size_t)ch * PSTRIDE + 4096 + t];
        sv[t] = s;
    }
    __syncthreads();

    // cov -> BUF0
    const float invM = 1.0f / (float)MM;
#pragma unroll
    for (int rr = 0; rr < 16; ++rr) {
        int e = t + rr * 256;
        float g = 0.f;
        for (int ch = 0; ch < nchunk; ++ch) g += pb[(size_t)ch * PSTRIDE + e];
        int r = e >> 6, c = e & 63;
        BUF[0][r * 65 + c] = g * invM - sv[r] * sv[c] * invM * invM;
    }
    __syncthreads();

    if (t == 0) {
        float tr = 0.f;
        for (int c = 0; c < 64; ++c) tr += BUF[0][c * 66];
        scal[0] = 1.0f / tr;
        scal[1] = sqrtf(tr);
    }
    __syncthreads();
    float itr = scal[0];

    // A = cov / trace  (in BUF0)
#pragma unroll
    for (int rr = 0; rr < 16; ++rr) {
        int e = t + rr * 256;
        BUF[0][(e >> 6) * 65 + (e & 63)] *= itr;
    }

    float *pA = BUF[0], *pY = BUF[1], *pZ = BUF[2], *pT = BUF[3], *pS = BUF[4];

    // Y = A @ (1.5I - 0.5A) = 1.5A - 0.5 A@A ;  Z = 1.5I - 0.5A
    mm64(pA, pA, pT, t);
#pragma unroll
    for (int rr = 0; rr < 16; ++rr) {
        int e = t + rr * 256;
        int r = e >> 6, c = e & 63;
        float a = pA[r * 65 + c];
        pY[r * 65 + c] = 1.5f * a - 0.5f * pT[r * 65 + c];
        pZ[r * 65 + c] = (r == c ? 1.5f : 0.f) - 0.5f * a;
    }

    for (int it = 0; it < 3; ++it) {
        mm64(pZ, pY, pT, t);                       // T = Z@Y
#pragma unroll
        for (int rr = 0; rr < 16; ++rr) {          // ZY = 1.5I - 0.5T (in pT)
            int e = t + rr * 256;
            int r = e >> 6, c = e & 63;
            pT[r * 65 + c] = (r == c ? 1.5f : 0.f) - 0.5f * pT[r * 65 + c];
        }
        mm64(pY, pT, pS, t);                       // Ynew = Y@ZY
        mm64(pT, pZ, pA, t);                       // Znew = ZY@Z
        float* tmp;
        tmp = pY; pY = pS; pS = tmp;
        tmp = pZ; pZ = pA; pA = tmp;
    }
    mm64(pZ, pY, pT, t);                           // T = Z@Y
#pragma unroll
    for (int rr = 0; rr < 16; ++rr) {
        int e = t + rr * 256;
        int r = e >> 6, c = e & 63;
        pT[r * 65 + c] = (r == c ? 1.5f : 0.f) - 0.5f * pT[r * 65 + c];
    }
    mm64(pY, pT, pS, t);                           // S = final ZY (pre-scale)

    // v[c] = sqrt(tr)/64 * sum_i S[i][c]
    if (t < 64) {
        float v = 0.f;
        for (int i = 0; i < 64; ++i) v += pS[i * 65 + t];
        sv[t] = v * scal[1] * (1.0f / 64.0f);
    }
    __syncthreads();
    if (t < 8) {
        float h = b1[t];
        for (int c = 0; c < 64; ++c) h += sv[c] * w1[t * 64 + c];
        hid8[t] = h > 0.f ? h : 0.f;
    }
    __syncthreads();
    if (t < 64) {
        float p = b2[t];
        for (int h = 0; h < 8; ++h) p += hid8[h] * w2[t * 8 + h];
        att[b * 64 + t] = 1.0f / (1.0f + expf(-p));
    }
}

// ---------------------------------------------------------------------------
// Kernel 3: out[b,c,:] = att[b,c] * x[b,c,:]   (streaming, float4)
// ---------------------------------------------------------------------------
__global__ __launch_bounds__(256) void scale_out(const float* __restrict__ x,
                                                 const float* __restrict__ att,
                                                 float* __restrict__ out) {
    size_t i = (size_t)blockIdx.x * blockDim.x + threadIdx.x;
    const size_t total4 = (size_t)BATCH * CH * MM / 4;
    const size_t stride = (size_t)gridDim.x * blockDim.x;
    const float4* x4 = reinterpret_cast<const float4*>(x);
    float4* o4 = reinterpret_cast<float4*>(out);
    for (; i < total4; i += stride) {
        int bc = (int)(i >> 14);        // MM/4 = 16384 float4 per channel
        float a = att[bc];
        float4 v = x4[i];
        v.x *= a; v.y *= a; v.z *= a; v.w *= a;
        o4[i] = v;
    }
}

// ---------------------------------------------------------------------------
extern "C" void kernel_launch(void* const* d_in, const int* in_sizes, int n_in,
                              void* d_out, int out_size, void* d_ws, size_t ws_size,
                              hipStream_t stream) {
    const float* x  = (const float*)d_in[0];
    const float* w1 = (const float*)d_in[1];
    const float* b1 = (const float*)d_in[2];
    const float* w2 = (const float*)d_in[3];
    const float* b2 = (const float*)d_in[4];
    float* out = (float*)d_out;
    float* ws  = (float*)d_ws;

    // pick chunk count to fit workspace
    int nchunk = 32;
    for (;;) {
        size_t need = ((size_t)BATCH * nchunk * PSTRIDE + (size_t)BATCH * CH) * sizeof(float);
        if (need <= ws_size || nchunk == 1) break;
        nchunk >>= 1;
    }
    int chunk_m = MM / nchunk;

    float* att = ws + (size_t)BATCH * nchunk * PSTRIDE;

    gram_partial<<<BATCH * nchunk, 256, 0, stream>>>(x, ws, nchunk, chunk_m);
    ns_att<<<BATCH, 256, 0, stream>>>(ws, w1, b1, w2, b2, att, nchunk);
    scale_out<<<2048, 256, 0, stream>>>(x, att, out);
}

// Round 2
// 248.855 us; speedup vs baseline: 1.6540x; 1.6540x over previous
//
#include <hip/hip_runtime.h>
#include <math.h>

#define BATCH 16
#define CH    64
#define MM    65536          // 256*256
#define PSTRIDE 4160         // 64*64 gram + 64 sums per partial block
#define MT    256            // m per LDS tile in gram kernel
#define SF    68             // f32 LDS row stride in ns kernel (17*16B aligned)

typedef __attribute__((ext_vector_type(8))) short s16x8;
typedef __attribute__((ext_vector_type(4))) float f32x4;

__device__ __forceinline__ unsigned short f2bf(float f) {
    unsigned u = __builtin_bit_cast(unsigned, f);
    u += 0x7fff + ((u >> 16) & 1);          // round-to-nearest-even
    return (unsigned short)(u >> 16);
}
__device__ __forceinline__ float bf2f(unsigned short h) {
    return __builtin_bit_cast(float, (unsigned)h << 16);
}

// ---------------------------------------------------------------------------
// Kernel 1: partial Gram via bf16 MFMA + f32 channel sums.
// Block = 256 thr (4 waves). LDS tile: 64 ch x 256 m bf16, XOR-swizzled.
// Wave w owns output rows [w*16, w*16+16) -> no cross-wave reduction.
// Gram is symmetric, so B-operand fragments are row-reads of the same tile.
// ---------------------------------------------------------------------------
__global__ __launch_bounds__(256) void gram_mfma(const float* __restrict__ x,
                                                 float* __restrict__ part,
                                                 int nchunk, int chunk_m) {
    int blk = blockIdx.x;
    int b = blk / nchunk, chunk = blk % nchunk;
    const float* xb = x + (size_t)b * CH * MM + (size_t)chunk * chunk_m;

    __shared__ unsigned short xs[CH * MT];   // 32 KiB, row stride 512 B
    __shared__ float csum[CH];

    int t = threadIdx.x;
    int w = t >> 6, l = t & 63;
    int lg = l >> 4, lr = l & 15;

    f32x4 acc[4];
    const f32x4 zero = {0.f, 0.f, 0.f, 0.f};
#pragma unroll
    for (int i = 0; i < 4; ++i) acc[i] = zero;
    float ssum[16];
#pragma unroll
    for (int r = 0; r < 16; ++r) ssum[r] = 0.f;

    int ntile = chunk_m / MT;
    int arow = w * 16 + lr;
    int abase = arow * 512;
    int aswz = (arow & 7) << 4;

    for (int tile = 0; tile < ntile; ++tile) {
        int mbase = tile * MT;
        __syncthreads();
        // stage 64 x 256 f32 -> bf16 LDS (swizzled). 4096 float4 / 256 thr.
#pragma unroll
        for (int r = 0; r < 16; ++r) {
            int idx4 = t + r * 256;
            int row = idx4 >> 6;              // 64 float4 per row
            int col = (idx4 & 63) << 2;       // f32 column
            float4 v = *reinterpret_cast<const float4*>(
                xb + (size_t)row * MM + mbase + col);
            ssum[r] += v.x + v.y + v.z + v.w;
            ushort4 p;
            p.x = f2bf(v.x); p.y = f2bf(v.y); p.z = f2bf(v.z); p.w = f2bf(v.w);
            int byte = (row * 512 + col * 2) ^ ((row & 7) << 4);
            *reinterpret_cast<ushort4*>(reinterpret_cast<char*>(xs) + byte) = p;
        }
        __syncthreads();
        // MFMA over K=256 (8 chunks of 32)
#pragma unroll
        for (int kk = 0; kk < 8; ++kk) {
            int kbyte = kk * 64 + lg * 16;
            s16x8 af = *reinterpret_cast<const s16x8*>(
                reinterpret_cast<const char*>(xs) + ((abase + kbyte) ^ aswz));
#pragma unroll
            for (int ct = 0; ct < 4; ++ct) {
                int brow = ct * 16 + lr;
                s16x8 bf = *reinterpret_cast<const s16x8*>(
                    reinterpret_cast<const char*>(xs) +
                    ((brow * 512 + kbyte) ^ ((brow & 7) << 4)));
                acc[ct] = __builtin_amdgcn_mfma_f32_16x16x32_bf16(af, bf, acc[ct], 0, 0, 0);
            }
        }
    }

    // write partial gram: C/D layout row=(lane>>4)*4+j, col=lane&15
    float* op = part + (size_t)blk * PSTRIDE;
#pragma unroll
    for (int ct = 0; ct < 4; ++ct)
#pragma unroll
        for (int j = 0; j < 4; ++j)
            op[(w * 16 + lg * 4 + j) * 64 + ct * 16 + lr] = acc[ct][j];

    // channel sums: ssum[r] belongs to channel w + 4r (whole wave shares it)
#pragma unroll
    for (int r = 0; r < 16; ++r) {
        float v = ssum[r];
#pragma unroll
        for (int m = 32; m >= 1; m >>= 1) v += __shfl_xor(v, m);
        if (l == 0) csum[w + 4 * r] = v;
    }
    __syncthreads();
    if (t < 64) op[4096 + t] = csum[t];
}

// ---------------------------------------------------------------------------
// Kernel 1b: reduce nchunk partials -> one 4160-float block per batch
// ---------------------------------------------------------------------------
__global__ __launch_bounds__(256) void reduce_parts(const float* __restrict__ part,
                                                    float* __restrict__ red,
                                                    int nchunk) {
    int b = blockIdx.y;
    int i = blockIdx.x * 256 + threadIdx.x;      // float4 index, 1040 total
    if (i >= PSTRIDE / 4) return;
    const float4* p = reinterpret_cast<const float4*>(part + (size_t)b * nchunk * PSTRIDE) + i;
    float4 s = {0.f, 0.f, 0.f, 0.f};
    for (int ch = 0; ch < nchunk; ++ch) {
        float4 v = p[(size_t)ch * (PSTRIDE / 4)];
        s.x += v.x; s.y += v.y; s.z += v.z; s.w += v.w;
    }
    reinterpret_cast<float4*>(red + (size_t)b * PSTRIDE)[i] = s;
}

// ---------------------------------------------------------------------------
// Kernel 2: cov -> Newton-Schulz(5) via split-bf16 MFMA -> FC -> att.
// One block (256 thr, 4 waves) per batch. All NS iterates are polynomials in
// the symmetric cov => symmetric => B-operand column slices == row slices.
// Split precision: C = hi*hi + hi*lo + lo*hi  (~2^-16 relative error).
// ---------------------------------------------------------------------------
__device__ __forceinline__ void cvt_store(const float* __restrict__ M, int row,
                                          int col, unsigned short* Hp,
                                          unsigned short* Lp) {
    float4 v = *reinterpret_cast<const float4*>(M + row * SF + col);
    ushort4 h, lo;
    h.x = f2bf(v.x); lo.x = f2bf(v.x - bf2f(h.x));
    h.y = f2bf(v.y); lo.y = f2bf(v.y - bf2f(h.y));
    h.z = f2bf(v.z); lo.z = f2bf(v.z - bf2f(h.z));
    h.w = f2bf(v.w); lo.w = f2bf(v.w - bf2f(h.w));
    int byte = (row * 128 + col * 2) ^ ((row & 7) << 4);
    *reinterpret_cast<ushort4*>(reinterpret_cast<char*>(Hp) + byte) = h;
    *reinterpret_cast<ushort4*>(reinterpret_cast<char*>(Lp) + byte) = lo;
}

__device__ __forceinline__ void mm64(const float* __restrict__ A,
                                     const float* __restrict__ B,
                                     float* __restrict__ C,
                                     unsigned short* AHp, unsigned short* ALp,
                                     unsigned short* BHp, unsigned short* BLp,
                                     int t) {
    int w = t >> 6, l = t & 63, lg = l >> 4, lr = l & 15;
    __syncthreads();                       // operands (f32) ready
#pragma unroll
    for (int r = 0; r < 4; ++r) {
        int e4 = t + r * 256;              // 1024 float4 = 4096 elements
        int row = e4 >> 4;                 // 16 float4 per row
        int col = (e4 & 15) << 2;
        cvt_store(A, row, col, AHp, ALp);
        cvt_store(B, row, col, BHp, BLp);
    }
    __syncthreads();
    f32x4 acc[4];
    const f32x4 zero = {0.f, 0.f, 0.f, 0.f};
#pragma unroll
    for (int i = 0; i < 4; ++i) acc[i] = zero;
    int arow = w * 16 + lr;
#pragma unroll
    for (int kk = 0; kk < 2; ++kk) {
        int kbyte = kk * 64 + lg * 16;
        int abyte = (arow * 128 + kbyte) ^ ((arow & 7) << 4);
        s16x8 ah = *reinterpret_cast<const s16x8*>(reinterpret_cast<const char*>(AHp) + abyte);
        s16x8 al = *reinterpret_cast<const s16x8*>(reinterpret_cast<const char*>(ALp) + abyte);
#pragma unroll
        for (int ct = 0; ct < 4; ++ct) {
            int brow = ct * 16 + lr;
            int bbyte = (brow * 128 + kbyte) ^ ((brow & 7) << 4);
            s16x8 bh = *reinterpret_cast<const s16x8*>(reinterpret_cast<const char*>(BHp) + bbyte);
            s16x8 bl = *reinterpret_cast<const s16x8*>(reinterpret_cast<const char*>(BLp) + bbyte);
            acc[ct] = __builtin_amdgcn_mfma_f32_16x16x32_bf16(ah, bh, acc[ct], 0, 0, 0);
            acc[ct] = __builtin_amdgcn_mfma_f32_16x16x32_bf16(ah, bl, acc[ct], 0, 0, 0);
            acc[ct] = __builtin_amdgcn_mfma_f32_16x16x32_bf16(al, bh, acc[ct], 0, 0, 0);
        }
    }
#pragma unroll
    for (int ct = 0; ct < 4; ++ct)
#pragma unroll
        for (int j = 0; j < 4; ++j)
            C[(w * 16 + lg * 4 + j) * SF + ct * 16 + lr] = acc[ct][j];
    __syncthreads();                       // result visible
}

__global__ __launch_bounds__(256) void ns_att(const float* __restrict__ red,
                                              const float* __restrict__ w1,
                                              const float* __restrict__ b1,
                                              const float* __restrict__ w2,
                                              const float* __restrict__ b2,
                                              float* __restrict__ att) {
    __shared__ float BUF[5][64 * SF];
    __shared__ unsigned short AH[64 * 64], AL[64 * 64], BH[64 * 64], BL[64 * 64];
    __shared__ float sv[64];
    __shared__ float hid8[8];
    __shared__ float scal[2];

    int b = blockIdx.x, t = threadIdx.x;
    const float* pb = red + (size_t)b * PSTRIDE;

    if (t < 64) sv[t] = pb[4096 + t];
    __syncthreads();

    // cov -> BUF0
    const float invM = 1.0f / (float)MM;
    const float invM2 = invM * invM;
#pragma unroll
    for (int r = 0; r < 4; ++r) {
        int e4 = t + r * 256;
        int row = e4 >> 4;
        int col = (e4 & 15) << 2;
        float4 g = *(reinterpret_cast<const float4*>(pb) + e4);
        float sr = sv[row] * invM2;
        BUF[0][row * SF + col]     = g.x * invM - sr * sv[col];
        BUF[0][row * SF + col + 1] = g.y * invM - sr * sv[col + 1];
        BUF[0][row * SF + col + 2] = g.z * invM - sr * sv[col + 2];
        BUF[0][row * SF + col + 3] = g.w * invM - sr * sv[col + 3];
    }
    __syncthreads();

    if (t == 0) {
        float tr = 0.f;
        for (int c = 0; c < 64; ++c) tr += BUF[0][c * SF + c];
        scal[0] = 1.0f / tr;
        scal[1] = sqrtf(tr);
    }
    __syncthreads();
    float itr = scal[0];
#pragma unroll
    for (int rr = 0; rr < 16; ++rr) {
        int e = t + rr * 256;
        BUF[0][(e >> 6) * SF + (e & 63)] *= itr;
    }

    float *pA = BUF[0], *pY = BUF[1], *pZ = BUF[2], *pT = BUF[3], *pS = BUF[4];

    // Y = 1.5A - 0.5 A@A ;  Z = 1.5I - 0.5A
    mm64(pA, pA, pT, AH, AL, BH, BL, t);
#pragma unroll
    for (int rr = 0; rr < 16; ++rr) {
        int e = t + rr * 256;
        int r = e >> 6, c = e & 63;
        float a = pA[r * SF + c];
        pY[r * SF + c] = 1.5f * a - 0.5f * pT[r * SF + c];
        pZ[r * SF + c] = (r == c ? 1.5f : 0.f) - 0.5f * a;
    }

    for (int it = 0; it < 3; ++it) {
        mm64(pZ, pY, pT, AH, AL, BH, BL, t);       // T = Z@Y
#pragma unroll
        for (int rr = 0; rr < 16; ++rr) {          // ZY = 1.5I - 0.5T (in pT)
            int e = t + rr * 256;
            int r = e >> 6, c = e & 63;
            pT[r * SF + c] = (r == c ? 1.5f : 0.f) - 0.5f * pT[r * SF + c];
        }
        mm64(pY, pT, pS, AH, AL, BH, BL, t);       // Ynew = Y@ZY
        mm64(pT, pZ, pA, AH, AL, BH, BL, t);       // Znew = ZY@Z
        float* tmp;
        tmp = pY; pY = pS; pS = tmp;
        tmp = pZ; pZ = pA; pA = tmp;
    }
    mm64(pZ, pY, pT, AH, AL, BH, BL, t);           // T = Z@Y
#pragma unroll
    for (int rr = 0; rr < 16; ++rr) {
        int e = t + rr * 256;
        int r = e >> 6, c = e & 63;
        pT[r * SF + c] = (r == c ? 1.5f : 0.f) - 0.5f * pT[r * SF + c];
    }
    mm64(pY, pT, pS, AH, AL, BH, BL, t);           // S = final ZY (pre-scale)

    // v[c] = sqrt(tr)/64 * sum_i S[i][c]  (S symmetric -> row sum)
    if (t < 64) {
        float v = 0.f;
        for (int i = 0; i < 64; ++i) v += pS[t * SF + i];
        sv[t] = v * scal[1] * (1.0f / 64.0f);
    }
    __syncthreads();
    if (t < 8) {
        float h = b1[t];
        for (int c = 0; c < 64; ++c) h += sv[c] * w1[t * 64 + c];
        hid8[t] = h > 0.f ? h : 0.f;
    }
    __syncthreads();
    if (t < 64) {
        float p = b2[t];
        for (int h = 0; h < 8; ++h) p += hid8[h] * w2[t * 8 + h];
        att[b * 64 + t] = 1.0f / (1.0f + expf(-p));
    }
}

// ---------------------------------------------------------------------------
// Kernel 3: out[b,c,:] = att[b,c] * x[b,c,:]   (streaming, float4)
// ---------------------------------------------------------------------------
__global__ __launch_bounds__(256) void scale_out(const float* __restrict__ x,
                                                 const float* __restrict__ att,
                                                 float* __restrict__ out) {
    size_t i = (size_t)blockIdx.x * blockDim.x + threadIdx.x;
    const size_t total4 = (size_t)BATCH * CH * MM / 4;
    const size_t stride = (size_t)gridDim.x * blockDim.x;
    const float4* x4 = reinterpret_cast<const float4*>(x);
    float4* o4 = reinterpret_cast<float4*>(out);
    for (; i < total4; i += stride) {
        int bc = (int)(i >> 14);        // MM/4 = 16384 float4 per channel
        float a = att[bc];
        float4 v = x4[i];
        v.x *= a; v.y *= a; v.z *= a; v.w *= a;
        o4[i] = v;
    }
}

// ---------------------------------------------------------------------------
extern "C" void kernel_launch(void* const* d_in, const int* in_sizes, int n_in,
                              void* d_out, int out_size, void* d_ws, size_t ws_size,
                              hipStream_t stream) {
    const float* x  = (const float*)d_in[0];
    const float* w1 = (const float*)d_in[1];
    const float* b1 = (const float*)d_in[2];
    const float* w2 = (const float*)d_in[3];
    const float* b2 = (const float*)d_in[4];
    float* out = (float*)d_out;
    float* ws  = (float*)d_ws;

    int nchunk = 32;
    for (;;) {
        size_t need = ((size_t)BATCH * nchunk * PSTRIDE + (size_t)BATCH * PSTRIDE +
                       (size_t)BATCH * CH) * sizeof(float);
        if (need <= ws_size || nchunk == 1) break;
        nchunk >>= 1;
    }
    int chunk_m = MM / nchunk;

    float* part = ws;
    float* red  = ws + (size_t)BATCH * nchunk * PSTRIDE;
    float* att  = red + (size_t)BATCH * PSTRIDE;

    gram_mfma<<<BATCH * nchunk, 256, 0, stream>>>(x, part, nchunk, chunk_m);
    reduce_parts<<<dim3((PSTRIDE / 4 + 255) / 256, BATCH), 256, 0, stream>>>(part, red, nchunk);
    ns_att<<<BATCH, 256, 0, stream>>>(red, w1, b1, w2, b2, att);
    scale_out<<<2048, 256, 0, stream>>>(x, att, out);
}